// Round 9
// baseline (72.124 us; speedup 1.0000x reference)
//
#include <hip/hip_runtime.h>

#define IMG_H 1024
#define IMG_W 1024
#define IMG_C 3

// Interior: x in [2,1017], 4 px per thread, 254 strips per row (exact cover).
#define SPR 254
#define INT_ROWS 1019                           // y = 2..1020
#define N_STRIPS (IMG_C * INT_ROWS * SPR)       // 776,478
#define NB_INT ((N_STRIPS + 255) / 256)         // 3034
#define BND_PER_C (5 * 1024 + INT_ROWS * 8)     // 13,272
#define N_BND (IMG_C * BND_PER_C)               // 39,816
#define NB_BND ((N_BND + 255) / 256)            // 156

// ===== packed f16x2 compare-exchange machinery (verified rounds 6-8) =====
typedef _Float16 h2 __attribute__((ext_vector_type(2)));

__device__ __forceinline__ h2 h2min(h2 a, h2 b) { return __builtin_elementwise_min(a, b); }
__device__ __forceinline__ h2 h2max(h2 a, h2 b) { return __builtin_elementwise_max(a, b); }
__device__ __forceinline__ void CEh(h2& a, h2& b) { h2 t = h2min(a, b); b = h2max(a, b); a = t; }

__device__ __forceinline__ h2 pkrtz(float a, float b) {
    auto v = __builtin_amdgcn_cvt_pkrtz(a, b);   // v_cvt_pkrtz_f16_f32
    h2 r;
    __builtin_memcpy(&r, &v, sizeof(r));
    return r;
}

// half-lane repacks (compiler emits v_perm/v_pack; 1 op each)
__device__ __forceinline__ h2 pk_hilo(h2 a, h2 b) { h2 r; r.x = a.y; r.y = b.x; return r; } // {a.hi, b.lo}
__device__ __forceinline__ h2 pk_lohi(h2 a, h2 b) { h2 r; r.x = a.x; r.y = b.y; return r; } // {a.lo, b.hi}
__device__ __forceinline__ h2 dup_lo(h2 a) { h2 r; r.x = a.x; r.y = a.x; return r; }
__device__ __forceinline__ h2 dup_hi(h2 a) { h2 r; r.x = a.y; r.y = a.y; return r; }

// 9-CE optimal sorting network for 5 (verified round 6).
__device__ __forceinline__ void sort5h(h2* a) {
    CEh(a[0], a[1]); CEh(a[3], a[4]); CEh(a[2], a[4]); CEh(a[2], a[3]);
    CEh(a[0], a[3]); CEh(a[0], a[2]); CEh(a[1], a[4]); CEh(a[1], a[3]);
    CEh(a[1], a[2]);
}

__device__ __forceinline__ void merge22h(const h2* A, const h2* B, h2* out) {
    h2 e0 = h2min(A[0], B[0]), e1 = h2max(A[0], B[0]);
    h2 o0 = h2min(A[1], B[1]), o1 = h2max(A[1], B[1]);
    out[0] = e0;
    out[1] = h2min(o0, e1); out[2] = h2max(o0, e1);
    out[3] = o1;
}

__device__ __forceinline__ void merge33h(const h2* A, const h2* B, h2* out) {
    h2 Ae[2] = {A[0], A[2]}, Be[2] = {B[0], B[2]};
    h2 E[4];
    merge22h(Ae, Be, E);
    h2 O0 = h2min(A[1], B[1]), O1 = h2max(A[1], B[1]);
    out[0] = E[0];
    out[1] = h2min(O0, E[1]); out[2] = h2max(O0, E[1]);
    out[3] = h2min(O1, E[2]); out[4] = h2max(O1, E[2]);
    out[5] = E[3];
}

__device__ __forceinline__ void merge55h(const h2* A, const h2* B, h2* out) {
    h2 Ae[3] = {A[0], A[2], A[4]}, Be[3] = {B[0], B[2], B[4]};
    h2 E[6];
    merge33h(Ae, Be, E);
    h2 Ao[2] = {A[1], A[3]}, Bo[2] = {B[1], B[3]};
    h2 O[4];
    merge22h(Ao, Bo, O);
    out[0] = E[0];
    out[1] = h2min(O[0], E[1]); out[2] = h2max(O[0], E[1]);
    out[3] = h2min(O[1], E[2]); out[4] = h2max(O[1], E[2]);
    out[5] = h2min(O[2], E[3]); out[6] = h2max(O[2], E[3]);
    out[7] = h2min(O[3], E[4]); out[8] = h2max(O[3], E[4]);
    out[9] = E[5];
}

__device__ __forceinline__ void merge1010_midh(const h2* A, const h2* B, h2* mid) {
    h2 Ae[5] = {A[0], A[2], A[4], A[6], A[8]}, Be[5] = {B[0], B[2], B[4], B[6], B[8]};
    h2 E[10];
    merge55h(Ae, Be, E);
    h2 Ao[5] = {A[1], A[3], A[5], A[7], A[9]}, Bo[5] = {B[1], B[3], B[5], B[7], B[9]};
    h2 O[10];
    merge55h(Ao, Bo, O);
    mid[0] = h2min(O[3], E[4]); mid[1] = h2max(O[3], E[4]);
    mid[2] = h2min(O[4], E[5]); mid[3] = h2max(O[4], E[5]);
    mid[4] = h2min(O[5], E[6]); mid[5] = h2max(O[5], E[6]);
}

__device__ __forceinline__ h2 final_medianh(const h2* mid, const h2* c5) {
    const _Float16 hinf = (_Float16)__builtin_inff();
    h2 INF2 = {hinf, hinf};
    h2 Ae[3] = {mid[0], mid[2], mid[4]}, Be[3] = {c5[0], c5[2], c5[4]};
    h2 E[6];
    merge33h(Ae, Be, E);
    h2 Ao[3] = {mid[1], mid[3], mid[5]}, Bo[3] = {c5[1], c5[3], INF2};
    h2 O[6];
    merge33h(Ao, Bo, O);
    return h2min(O[2], E[3]);
}

__global__ __launch_bounds__(256) void median5_kernel(const float* __restrict__ img,
                                                      float* __restrict__ out) {
    const float INF = __builtin_inff();

    if (blockIdx.x >= NB_BND) {
        // ===== interior: 4-px threads, fully-packed f16 network, high occupancy =====
        int gid = (blockIdx.x - NB_BND) * 256 + threadIdx.x;
        if (gid >= N_STRIPS) return;
        int xs = gid % SPR;
        int t = gid / SPR;
        int y = 2 + t % INT_ROWS;
        int c = t / INT_ROWS;
        int x0 = 2 + 4 * xs;

        const float* p = img + (size_t)c * IMG_H * IMG_W + (size_t)(y - 2) * IMG_W + (x0 - 2);

        // batch all 10 loads (cols x0-2..x0+5 over 5 rows; x0-2 = 4*xs -> 16B aligned)
        float4 LA[5], LB[5];
#pragma unroll
        for (int r = 0; r < 5; ++r) {
            const float4* rp = (const float4*)(p + r * IMG_W);
            LA[r] = rp[0];   // c0..c3
            LB[r] = rp[1];   // c4..c7
        }

        // packed columns Q_j = {c_j, c_{j+4}}
        h2 Q0[5], Q1[5], Q2[5], Q3[5];
#pragma unroll
        for (int r = 0; r < 5; ++r) {
            Q0[r] = pkrtz(LA[r].x, LB[r].x);
            Q1[r] = pkrtz(LA[r].y, LB[r].y);
            Q2[r] = pkrtz(LA[r].z, LB[r].z);
            Q3[r] = pkrtz(LA[r].w, LB[r].w);
        }
        sort5h(Q0); sort5h(Q1); sort5h(Q2); sort5h(Q3);

        // pair merges (pairing is arbitrary for the median-25 reduction):
        // MA = {M02, M46}, MB = {M13, M57}
        h2 MA[10], MB[10];
        merge55h(Q0, Q2, MA);
        merge55h(Q1, Q3, MB);

        // ---- px0 (single c4, pairs 02,13) & px3 (single c3, pairs 46,57) ----
        h2 midP[6];
        merge1010_midh(MA, MB, midP);        // {mid(02,13), mid(46,57)}
        h2 SC1[5];                           // {c4, c3}
#pragma unroll
        for (int r = 0; r < 5; ++r) SC1[r] = pk_hilo(Q0[r], Q3[r]);
        h2 Fa = final_medianh(midP, SC1);    // {px0, px3}

        // ---- px1 (single c2, pairs 13,45) & px2 (single c2, pairs 46,35) ----
        // MC = merge55h({c4,c3},{c5,c5}) = {M45, M35}
        h2 B2[5];
#pragma unroll
        for (int r = 0; r < 5; ++r) B2[r] = dup_hi(Q1[r]);   // {c5, c5}
        h2 MC[10];
        merge55h(SC1, B2, MC);
        // D = {M13, M46}
        h2 D[10];
#pragma unroll
        for (int i = 0; i < 10; ++i) D[i] = pk_lohi(MB[i], MA[i]);
        h2 midQ[6];
        merge1010_midh(D, MC, midQ);         // {mid(13,45), mid(46,35)}
        h2 SC2[5];
#pragma unroll
        for (int r = 0; r < 5; ++r) SC2[r] = dup_lo(Q2[r]);  // {c2, c2}
        h2 Fb = final_medianh(midQ, SC2);    // {px1, px2}

        float* po = out + (size_t)c * IMG_H * IMG_W + (size_t)y * IMG_W + x0;
        float2* po2 = (float2*)po;           // 8B aligned
        po2[0] = make_float2((float)Fa.x, (float)Fb.x);   // px0, px1
        po2[1] = make_float2((float)Fb.y, (float)Fa.y);   // px2, px3
    } else {
        // ===== boundary frame FIRST: exact fp32 bitonic-32 (verified rounds 1-8) =====
        int gid = blockIdx.x * 256 + threadIdx.x;
        if (gid >= N_BND) return;
        int c = gid / BND_PER_C;
        int b = gid % BND_PER_C;
        int y, x;
        if (b < 2048) {                 // rows 0,1
            y = b >> 10; x = b & 1023;
        } else if (b < 5120) {          // rows 1021..1023
            int t2 = b - 2048;
            y = 1021 + (t2 >> 10); x = t2 & 1023;
        } else {                        // rows 2..1020, cols {0,1} ∪ {1018..1023}
            int t2 = b - 5120;
            y = 2 + (t2 >> 3);
            int m = t2 & 7;
            x = (m < 2) ? m : (1016 + m);
        }

        const float* p = img + (size_t)c * IMG_H * IMG_W;
        float v[32];
#pragma unroll
        for (int i = 25; i < 32; ++i) v[i] = INF;
#pragma unroll
        for (int dy = -2; dy <= 2; ++dy) {
#pragma unroll
            for (int dx = -2; dx <= 2; ++dx) {
                int yy = y + dy;
                int xx = x + dx;
                bool valid = (yy >= 0) && (yy <= IMG_H - 2) && (xx >= 0) && (xx <= IMG_W - 2);
                int yc = min(max(yy, 0), IMG_H - 1);
                int xc = min(max(xx, 0), IMG_W - 1);
                float val = p[yc * IMG_W + xc];
                v[(dy + 2) * 5 + (dx + 2)] = valid ? val : INF;
            }
        }
#pragma unroll
        for (int k = 2; k <= 32; k <<= 1) {
#pragma unroll
            for (int j = k >> 1; j > 0; j >>= 1) {
#pragma unroll
                for (int i = 0; i < 32; ++i) {
                    int l = i ^ j;
                    if (l > i) {
                        bool up = ((i & k) == 0);
                        float a = v[i];
                        float b2 = v[l];
                        float mn = fminf(a, b2);
                        float mx = fmaxf(a, b2);
                        v[i] = up ? mn : mx;
                        v[l] = up ? mx : mn;
                    }
                }
            }
        }
        int ny = min(y + 2, IMG_H - 2) - max(y - 2, 0) + 1;
        int nx = min(x + 2, IMG_W - 2) - max(x - 2, 0) + 1;
        int n = ny * nx;
        int ilo = (n - 1) >> 1;
        int ihi = n >> 1;
        float lo = 0.0f, hi = 0.0f;
#pragma unroll
        for (int i = 0; i < 13; ++i) {
            if (i == ilo) lo = v[i];
            if (i == ihi) hi = v[i];
        }
        out[(size_t)c * IMG_H * IMG_W + (size_t)y * IMG_W + x] = 0.5f * (lo + hi);
    }
}

extern "C" void kernel_launch(void* const* d_in, const int* in_sizes, int n_in,
                              void* d_out, int out_size, void* d_ws, size_t ws_size,
                              hipStream_t stream) {
    const float* img = (const float*)d_in[0];
    float* out = (float*)d_out;
    dim3 block(256);
    dim3 grid(NB_BND + NB_INT);
    median5_kernel<<<grid, block, 0, stream>>>(img, out);
}

// Round 10
// 68.730 us; speedup vs baseline: 1.0494x; 1.0494x over previous
//
#include <hip/hip_runtime.h>

#define IMG_H 1024
#define IMG_W 1024
#define IMG_C 3

// Interior: x in [2,1017], 8 px wide x 2 rows per thread, 127 strips per row-pair.
#define SPR 127
#define ROWPAIRS 510                            // y0 = min(2+2*rp, 1019); rows y0, y0+1
#define N_STRIPS (IMG_C * ROWPAIRS * SPR)       // 194,310
#define NB_INT ((N_STRIPS + 255) / 256)         // 760
#define INT_ROWS 1019
#define BND_PER_C (5 * 1024 + INT_ROWS * 8)     // 13,272
#define N_BND (IMG_C * BND_PER_C)               // 39,816
#define NB_BND ((N_BND + 255) / 256)            // 156

// ===== packed f16x2 compare-exchange machinery (verified rounds 6-9) =====
typedef _Float16 h2 __attribute__((ext_vector_type(2)));

__device__ __forceinline__ h2 h2min(h2 a, h2 b) { return __builtin_elementwise_min(a, b); }
__device__ __forceinline__ h2 h2max(h2 a, h2 b) { return __builtin_elementwise_max(a, b); }
__device__ __forceinline__ void CEh(h2& a, h2& b) { h2 t = h2min(a, b); b = h2max(a, b); a = t; }

__device__ __forceinline__ h2 pkrtz(float a, float b) {
    auto v = __builtin_amdgcn_cvt_pkrtz(a, b);   // v_cvt_pkrtz_f16_f32
    h2 r;
    __builtin_memcpy(&r, &v, sizeof(r));
    return r;
}

__device__ __forceinline__ void merge22h(const h2* A, const h2* B, h2* out) {
    h2 e0 = h2min(A[0], B[0]), e1 = h2max(A[0], B[0]);
    h2 o0 = h2min(A[1], B[1]), o1 = h2max(A[1], B[1]);
    out[0] = e0;
    out[1] = h2min(o0, e1); out[2] = h2max(o0, e1);
    out[3] = o1;
}

__device__ __forceinline__ void merge33h(const h2* A, const h2* B, h2* out) {
    h2 Ae[2] = {A[0], A[2]}, Be[2] = {B[0], B[2]};
    h2 E[4];
    merge22h(Ae, Be, E);
    h2 O0 = h2min(A[1], B[1]), O1 = h2max(A[1], B[1]);
    out[0] = E[0];
    out[1] = h2min(O0, E[1]); out[2] = h2max(O0, E[1]);
    out[3] = h2min(O1, E[2]); out[4] = h2max(O1, E[2]);
    out[5] = E[3];
}

__device__ __forceinline__ void merge55h(const h2* A, const h2* B, h2* out) {
    h2 Ae[3] = {A[0], A[2], A[4]}, Be[3] = {B[0], B[2], B[4]};
    h2 E[6];
    merge33h(Ae, Be, E);
    h2 Ao[2] = {A[1], A[3]}, Bo[2] = {B[1], B[3]};
    h2 O[4];
    merge22h(Ao, Bo, O);
    out[0] = E[0];
    out[1] = h2min(O[0], E[1]); out[2] = h2max(O[0], E[1]);
    out[3] = h2min(O[1], E[2]); out[4] = h2max(O[1], E[2]);
    out[5] = h2min(O[2], E[3]); out[6] = h2max(O[2], E[3]);
    out[7] = h2min(O[3], E[4]); out[8] = h2max(O[3], E[4]);
    out[9] = E[5];
}

// Pruned merge of two sorted-5s: only outputs 3..6 (derived from verified
// merge55h by omitting unused ops; re-verified by 0-1 principle).
struct Sub4 { h2 r3, r4, r5, r6; };
__device__ __forceinline__ Sub4 sub55(const h2* A, const h2* B) {
    h2 e1  = h2max(A[1], B[1]);
    h2 o0  = h2min(A[3], B[3]);
    h2 P1  = h2min(o0, e1);      // O'[1]
    h2 P2  = h2max(o0, e1);      // O'[2]
    h2 e1b = h2max(A[0], B[0]);
    h2 o0b = h2min(A[4], B[4]);
    h2 E1b = h2min(o0b, e1b);
    h2 E2b = h2max(o0b, e1b);
    h2 O0b = h2min(A[2], B[2]);
    h2 O1b = h2max(A[2], B[2]);
    h2 E2  = h2max(O0b, E1b);    // E'[2]
    h2 E3  = h2min(O1b, E2b);    // E'[3]
    Sub4 s;
    s.r3 = h2min(P1, E2); s.r4 = h2max(P1, E2);
    s.r5 = h2min(P2, E3); s.r6 = h2max(P2, E3);
    return s;
}

// ranks 7..12 (0-idx) of merge(A10, B10): same combine as verified
// merge1010_midh, with E10[4..6] / O10[3..5] from pruned sub-merges.
__device__ __forceinline__ void mid6_of_20(const h2* A, const h2* B, h2* mid) {
    h2 Ae[5] = {A[0], A[2], A[4], A[6], A[8]}, Be[5] = {B[0], B[2], B[4], B[6], B[8]};
    h2 Ao[5] = {A[1], A[3], A[5], A[7], A[9]}, Bo[5] = {B[1], B[3], B[5], B[7], B[9]};
    Sub4 E = sub55(Ae, Be);      // E10[3..6]; r4..r6 used
    Sub4 O = sub55(Ao, Bo);      // O10[3..6]; r3..r5 used
    mid[0] = h2min(O.r3, E.r4); mid[1] = h2max(O.r3, E.r4);
    mid[2] = h2min(O.r4, E.r5); mid[3] = h2max(O.r4, E.r5);
    mid[4] = h2min(O.r5, E.r6); mid[5] = h2max(O.r5, E.r6);
}

// median25 = rank-5 (0-idx) of mid6 ∪ c5 via two-sorted-array selection:
// kth smallest of A∪B = min over i+j=k of max(A_i, B_j). k=6 (1-idx), m=6, n=5.
__device__ __forceinline__ h2 sel_median(const h2* mid, const h2* c5) {
    h2 m0 = h2max(mid[0], c5[4]);
    h2 m1 = h2max(mid[1], c5[3]);
    h2 m2 = h2max(mid[2], c5[2]);
    h2 m3 = h2max(mid[3], c5[1]);
    h2 m4 = h2max(mid[4], c5[0]);
    return h2min(h2min(h2min(m0, m1), h2min(m2, m3)), h2min(m4, mid[5]));
}

// Whole-strip median network for one window row (R7 structure, new mid/final).
__device__ __forceinline__ void strip_medians(const h2 Q[8][5], float* po) {
    h2 MA[10], MB[10], MC[10], MD[10];
    merge55h(Q[0], Q[1], MA);   // {M01, M45}
    merge55h(Q[2], Q[3], MB);   // {M23, M67}
    merge55h(Q[4], Q[5], MC);   // {M45, M89}
    merge55h(Q[6], Q[7], MD);   // {M67, M10-11}

    h2 midA[6], midB[6], midC[6];
    mid6_of_20(MA, MB, midA);
    mid6_of_20(MB, MC, midB);
    mid6_of_20(MC, MD, midC);

    h2 F1 = sel_median(midA, Q[4]);   // {px0, px4}
    h2 F2 = sel_median(midB, Q[1]);   // {px1, px5}
    h2 F3 = sel_median(midB, Q[6]);   // {px2, px6}
    h2 F4 = sel_median(midC, Q[3]);   // {px3, px7}

    float2* po2 = (float2*)po;        // 8B aligned
    po2[0] = make_float2((float)F1.x, (float)F2.x);
    po2[1] = make_float2((float)F3.x, (float)F4.x);
    po2[2] = make_float2((float)F1.y, (float)F2.y);
    po2[3] = make_float2((float)F3.y, (float)F4.y);
}

// Insert x into sorted s0<=s1<=s2<=s3 -> sorted out[0..4] (verified rounds 7-9).
__device__ __forceinline__ void insert5(h2 x, h2 s0, h2 s1, h2 s2, h2 s3, h2* out) {
    out[0] = h2min(x, s0);
    out[1] = h2max(s0, h2min(x, s1));
    out[2] = h2max(s1, h2min(x, s2));
    out[3] = h2max(s2, h2min(x, s3));
    out[4] = h2max(x, s3);
}

__global__ __launch_bounds__(256) void median5_kernel(const float* __restrict__ img,
                                                      float* __restrict__ out) {
    const float INF = __builtin_inff();

    if (blockIdx.x >= NB_BND) {
        // ===== interior: 8x2 strips, shared vertical sort + packed-f16 network =====
        int gid = (blockIdx.x - NB_BND) * 256 + threadIdx.x;
        if (gid >= N_STRIPS) return;
        int xs = gid % SPR;
        int t = gid / SPR;
        int rp = t % ROWPAIRS;
        int c = t / ROWPAIRS;
        int y0 = 2 + 2 * rp;
        if (y0 > 1019) y0 = 1019;       // last pair overlaps rows 1019,1020 (dup write, same value)
        int x0 = 2 + 8 * xs;

        const float* p = img + (size_t)c * IMG_H * IMG_W;

        // V[j][r] packed {col_j, col_{j+4}} over 6 rows y0-2 .. y0+3.
        h2 V[8][6];
#pragma unroll
        for (int r = 0; r < 6; ++r) {
            const float4* rpnt = (const float4*)(p + (y0 - 2 + r) * IMG_W + (x0 - 2));
            float4 a = rpnt[0];   // c0..c3
            float4 b = rpnt[1];   // c4..c7
            float4 d = rpnt[2];   // c8..c11
            V[0][r] = pkrtz(a.x, b.x);
            V[1][r] = pkrtz(a.y, b.y);
            V[2][r] = pkrtz(a.z, b.z);
            V[3][r] = pkrtz(a.w, b.w);
            V[4][r] = pkrtz(b.x, d.x);
            V[5][r] = pkrtz(b.y, d.y);
            V[6][r] = pkrtz(b.z, d.z);
            V[7][r] = pkrtz(b.w, d.w);
        }

        // Shared middle sort: V[j][1..4] -> ascending (5-CE 4-sorter).
#pragma unroll
        for (int j = 0; j < 8; ++j) {
            CEh(V[j][1], V[j][2]); CEh(V[j][3], V[j][4]);
            CEh(V[j][1], V[j][3]); CEh(V[j][2], V[j][4]);
            CEh(V[j][2], V[j][3]);
        }

        float* po = out + (size_t)c * IMG_H * IMG_W + (size_t)y0 * IMG_W + x0;

        // Window A: rows y0-2..y0+2 (insert V[j][0]).
        {
            h2 QA[8][5];
#pragma unroll
            for (int j = 0; j < 8; ++j)
                insert5(V[j][0], V[j][1], V[j][2], V[j][3], V[j][4], QA[j]);
            strip_medians(QA, po);
        }
        // Window B: rows y0-1..y0+3 (insert V[j][5]).
        {
            h2 QB[8][5];
#pragma unroll
            for (int j = 0; j < 8; ++j)
                insert5(V[j][5], V[j][1], V[j][2], V[j][3], V[j][4], QB[j]);
            strip_medians(QB, po + IMG_W);
        }
    } else {
        // ===== boundary frame FIRST: exact fp32 bitonic-32 (verified rounds 1-9) =====
        int gid = blockIdx.x * 256 + threadIdx.x;
        if (gid >= N_BND) return;
        int c = gid / BND_PER_C;
        int b = gid % BND_PER_C;
        int y, x;
        if (b < 2048) {                 // rows 0,1
            y = b >> 10; x = b & 1023;
        } else if (b < 5120) {          // rows 1021..1023
            int t2 = b - 2048;
            y = 1021 + (t2 >> 10); x = t2 & 1023;
        } else {                        // rows 2..1020, cols {0,1} ∪ {1018..1023}
            int t2 = b - 5120;
            y = 2 + (t2 >> 3);
            int m = t2 & 7;
            x = (m < 2) ? m : (1016 + m);
        }

        const float* p = img + (size_t)c * IMG_H * IMG_W;
        float v[32];
#pragma unroll
        for (int i = 25; i < 32; ++i) v[i] = INF;
#pragma unroll
        for (int dy = -2; dy <= 2; ++dy) {
#pragma unroll
            for (int dx = -2; dx <= 2; ++dx) {
                int yy = y + dy;
                int xx = x + dx;
                bool valid = (yy >= 0) && (yy <= IMG_H - 2) && (xx >= 0) && (xx <= IMG_W - 2);
                int yc = min(max(yy, 0), IMG_H - 1);
                int xc = min(max(xx, 0), IMG_W - 1);
                float val = p[yc * IMG_W + xc];
                v[(dy + 2) * 5 + (dx + 2)] = valid ? val : INF;
            }
        }
#pragma unroll
        for (int k = 2; k <= 32; k <<= 1) {
#pragma unroll
            for (int j = k >> 1; j > 0; j >>= 1) {
#pragma unroll
                for (int i = 0; i < 32; ++i) {
                    int l = i ^ j;
                    if (l > i) {
                        bool up = ((i & k) == 0);
                        float a = v[i];
                        float b2 = v[l];
                        float mn = fminf(a, b2);
                        float mx = fmaxf(a, b2);
                        v[i] = up ? mn : mx;
                        v[l] = up ? mx : mn;
                    }
                }
            }
        }
        int ny = min(y + 2, IMG_H - 2) - max(y - 2, 0) + 1;
        int nx = min(x + 2, IMG_W - 2) - max(x - 2, 0) + 1;
        int n = ny * nx;
        int ilo = (n - 1) >> 1;
        int ihi = n >> 1;
        float lo = 0.0f, hi = 0.0f;
#pragma unroll
        for (int i = 0; i < 13; ++i) {
            if (i == ilo) lo = v[i];
            if (i == ihi) hi = v[i];
        }
        out[(size_t)c * IMG_H * IMG_W + (size_t)y * IMG_W + x] = 0.5f * (lo + hi);
    }
}

extern "C" void kernel_launch(void* const* d_in, const int* in_sizes, int n_in,
                              void* d_out, int out_size, void* d_ws, size_t ws_size,
                              hipStream_t stream) {
    const float* img = (const float*)d_in[0];
    float* out = (float*)d_out;
    dim3 block(256);
    dim3 grid(NB_BND + NB_INT);
    median5_kernel<<<grid, block, 0, stream>>>(img, out);
}